// Round 1
// 161.137 us; speedup vs baseline: 1.0039x; 1.0039x over previous
//
#include <hip/hip_runtime.h>

// Problem constants
#define BB 4
#define CC 128
#define NN 512
#define TT 16
#define HH 4
#define DKK 32
// SCALE = sqrt(DK) = sqrt(32);  1/SCALE:
#define INV_SCALE 0.17677669529663687f

typedef __attribute__((ext_vector_type(8))) short bf16x8;
typedef __attribute__((ext_vector_type(4))) float f32x4;

// pack two floats to bf16 pair (RNE)
__device__ __forceinline__ unsigned int pk2bf(float a, float b) {
  unsigned int ua = __float_as_uint(a);
  ua = (ua + 0x7FFFu + ((ua >> 16) & 1u)) >> 16;
  unsigned int ub = __float_as_uint(b);
  ub = (ub + 0x7FFFu + ((ub >> 16) & 1u)) >> 16;
  return ua | (ub << 16);
}

// single float -> bf16 (RNE)
__device__ __forceinline__ ushort cv1(float f) {
  unsigned int u = __float_as_uint(f);
  return (ushort)((u + 0x7FFFu + ((u >> 16) & 1u)) >> 16);
}

// fast pack (round-half-up): v_add x2 + v_perm
__device__ __forceinline__ unsigned int pkfast(float a, float b) {
  unsigned int au = __float_as_uint(a) + 0x8000u;
  unsigned int bu = __float_as_uint(b) + 0x8000u;
  return __builtin_amdgcn_perm(bu, au, 0x07060302u);
}

// ---------------------------------------------------------------------------
// Kernel 1: MFMA Q/K projection -> bf16. Absorbs W f32->bf16 conversion
// (W is 2x64KB, L2-hot across the 256 blocks; RNE conversion in-register).
// ---------------------------------------------------------------------------
__global__ __launch_bounds__(256) void k_proj(const float* __restrict__ x,
                                              const float* __restrict__ Wq,
                                              const float* __restrict__ Wk,
                                              ushort* __restrict__ Qb,
                                              ushort* __restrict__ Kb) {
  __shared__ float xl[128 * 128];
  const int b = blockIdx.y;
  const int nt0 = blockIdx.x * 128;
  const int tid = threadIdx.x;
  const int w = tid >> 6, lane = tid & 63;
  const int lm = lane & 15, quad = lane >> 4;

  const float* xb = x + (size_t)b * 1048576 + nt0;
#pragma unroll
  for (int L = tid * 4; L < 16384; L += 1024) {
    int c = L >> 7, j = L & 127;
    *(float4*)(xl + L) = *(const float4*)(xb + c * 8192 + j);
  }

  const int o0 = w * 32;
  bf16x8 aq[2][4], ak[2][4];
#pragma unroll
  for (int ot = 0; ot < 2; ++ot)
#pragma unroll
    for (int kc = 0; kc < 4; ++kc) {
      int off = (o0 + ot * 16 + lm) * 128 + kc * 32 + quad * 8;
      float4 q0 = *(const float4*)(Wq + off);
      float4 q1 = *(const float4*)(Wq + off + 4);
      float4 k0 = *(const float4*)(Wk + off);
      float4 k1 = *(const float4*)(Wk + off + 4);
      union { uint4 u; bf16x8 v; } cq, ck;
      cq.u = make_uint4(pk2bf(q0.x, q0.y), pk2bf(q0.z, q0.w),
                        pk2bf(q1.x, q1.y), pk2bf(q1.z, q1.w));
      ck.u = make_uint4(pk2bf(k0.x, k0.y), pk2bf(k0.z, k0.w),
                        pk2bf(k1.x, k1.y), pk2bf(k1.z, k1.w));
      aq[ot][kc] = cq.v;
      ak[ot][kc] = ck.v;
    }
  __syncthreads();

  const int nq = nt0 >> 4;
#pragma unroll 2
  for (int jt = 0; jt < 8; ++jt) {
    bf16x8 bfr[4];
#pragma unroll
    for (int kc = 0; kc < 4; ++kc) {
      const float* sp = xl + (kc * 32 + quad * 8) * 128 + jt * 16 + lm;
      float f0 = sp[0],   f1 = sp[128], f2 = sp[256], f3 = sp[384];
      float f4 = sp[512], f5 = sp[640], f6 = sp[768], f7 = sp[896];
      uint4 u;
      u.x = pkfast(f0, f1);
      u.y = pkfast(f2, f3);
      u.z = pkfast(f4, f5);
      u.w = pkfast(f6, f7);
      union { uint4 u; bf16x8 v; } cv;
      cv.u = u;
      bfr[kc] = cv.v;
    }

    f32x4 accq0 = {0,0,0,0}, accq1 = {0,0,0,0};
    f32x4 acck0 = {0,0,0,0}, acck1 = {0,0,0,0};
#pragma unroll
    for (int kc = 0; kc < 4; ++kc) {
      accq0 = __builtin_amdgcn_mfma_f32_16x16x32_bf16(aq[0][kc], bfr[kc], accq0, 0, 0, 0);
      accq1 = __builtin_amdgcn_mfma_f32_16x16x32_bf16(aq[1][kc], bfr[kc], accq1, 0, 0, 0);
      acck0 = __builtin_amdgcn_mfma_f32_16x16x32_bf16(ak[0][kc], bfr[kc], acck0, 0, 0, 0);
      acck1 = __builtin_amdgcn_mfma_f32_16x16x32_bf16(ak[1][kc], bfr[kc], acck1, 0, 0, 0);
    }

    const size_t base = (size_t)b * 1048576 + (size_t)lm * 65536 + w * 16384 +
                        (size_t)(nq + jt) * 32 + quad * 4;
    uint2 uq0, uq1, uk0, uk1;
    uq0.x = pk2bf(accq0[0], accq0[1]); uq0.y = pk2bf(accq0[2], accq0[3]);
    uq1.x = pk2bf(accq1[0], accq1[1]); uq1.y = pk2bf(accq1[2], accq1[3]);
    uk0.x = pk2bf(acck0[0], acck0[1]); uk0.y = pk2bf(acck0[2], acck0[3]);
    uk1.x = pk2bf(acck1[0], acck1[1]); uk1.y = pk2bf(acck1[2], acck1[3]);
    *(uint2*)(Qb + base)      = uq0;
    *(uint2*)(Qb + base + 16) = uq1;
    *(uint2*)(Kb + base)      = uk0;
    *(uint2*)(Kb + base + 16) = uk1;
  }
}

// ---------------------------------------------------------------------------
// Kernel 2: MFMA scores + softmax + partial mean over (t,h).
// Now 4 groups of 16 (t,h) pairs (was 8x8): part shrinks 16MB -> 8MB, and
// each bf16 partial carries 16 fp32-accumulated terms (better precision).
// Grid (32 strips, 4 groups, 4 b), block = 256 threads (4 waves).
// ---------------------------------------------------------------------------
__global__ __launch_bounds__(256, 4) void k_scores(const ushort* __restrict__ Qb,
                                                   const ushort* __restrict__ Kb,
                                                   ushort* __restrict__ part) {
  __shared__ float SH[16 * 516];   // epilogue transpose only
  __shared__ float red[2][4][16];  // [pair parity][wave][row]
  const int strip = blockIdx.x, g = blockIdx.y, b = blockIdx.z;
  const int tid = threadIdx.x;
  const int w = tid >> 6, lane = tid & 63;
  const int lm = lane & 15, quad = lane >> 4;
  const int n0 = strip * 16;
  const int wcol0 = w * 128;

  float acc[32];
#pragma unroll
  for (int i = 0; i < 32; ++i) acc[i] = 0.f;

  for (int pi = 0; pi < 16; ++pi) {
    const int p = (g << 4) + pi;
    const size_t base = (size_t)((b * 16 + (p >> 2)) * 4 + (p & 3)) * 16384;
    bf16x8 afrag = *(const bf16x8*)(Qb + base + (size_t)(n0 + lm) * 32 + quad * 8);
    bf16x8 bfr[8];
#pragma unroll
    for (int ct = 0; ct < 8; ++ct)
      bfr[ct] = *(const bf16x8*)(Kb + base + (size_t)(wcol0 + ct * 16 + lm) * 32 + quad * 8);

    f32x4 d[8];
#pragma unroll
    for (int ct = 0; ct < 8; ++ct) {
      f32x4 z = {0.f, 0.f, 0.f, 0.f};
      d[ct] = __builtin_amdgcn_mfma_f32_16x16x32_bf16(afrag, bfr[ct], z, 0, 0, 0);
    }

    // exp in D-layout: lane's d[ct][r] is row quad*4+r, col wcol0+ct*16+lm
    float cur[32];
    float rp0 = 0.f, rp1 = 0.f, rp2 = 0.f, rp3 = 0.f;
#pragma unroll
    for (int ct = 0; ct < 8; ++ct) {
      float e0 = __expf(d[ct][0] * INV_SCALE);
      float e1 = __expf(d[ct][1] * INV_SCALE);
      float e2 = __expf(d[ct][2] * INV_SCALE);
      float e3 = __expf(d[ct][3] * INV_SCALE);
      cur[ct * 4 + 0] = e0; cur[ct * 4 + 1] = e1;
      cur[ct * 4 + 2] = e2; cur[ct * 4 + 3] = e3;
      rp0 += e0; rp1 += e1; rp2 += e2; rp3 += e3;
    }
    // reduce over the 16 lanes of this quad-group (cols of this wave)
#pragma unroll
    for (int m = 1; m < 16; m <<= 1) {
      rp0 += __shfl_xor(rp0, m);
      rp1 += __shfl_xor(rp1, m);
      rp2 += __shfl_xor(rp2, m);
      rp3 += __shfl_xor(rp3, m);
    }
    if (lm == 0) {
      red[pi & 1][w][quad * 4 + 0] = rp0;
      red[pi & 1][w][quad * 4 + 1] = rp1;
      red[pi & 1][w][quad * 4 + 2] = rp2;
      red[pi & 1][w][quad * 4 + 3] = rp3;
    }
    __syncthreads();
    // total rowsum across 4 waves (broadcast reads), then accumulate
#pragma unroll
    for (int r = 0; r < 4; ++r) {
      float rs = red[pi & 1][0][quad * 4 + r] + red[pi & 1][1][quad * 4 + r] +
                 red[pi & 1][2][quad * 4 + r] + red[pi & 1][3][quad * 4 + r];
      float inv = 1.0f / rs;
#pragma unroll
      for (int ct = 0; ct < 8; ++ct)
        acc[ct * 4 + r] = fmaf(cur[ct * 4 + r], inv, acc[ct * 4 + r]);
    }
  }

  // epilogue: transpose via LDS for coalesced bf16 stores
#pragma unroll
  for (int ct = 0; ct < 8; ++ct) {
#pragma unroll
    for (int r = 0; r < 4; ++r)
      SH[(quad * 4 + r) * 516 + wcol0 + ct * 16 + lm] = acc[ct * 4 + r];
  }
  __syncthreads();
  const int row = tid >> 4, colb = (tid & 15) * 4;
  ushort* po = part + ((size_t)((g * 4 + b) * 512 + n0 + row)) * 512 + colb;
#pragma unroll
  for (int k = 0; k < 8; ++k) {
    f32x4 v = *(const f32x4*)(SH + row * 516 + colb + k * 64);
    uint2 u;
    u.x = pk2bf(v[0], v[1]);
    u.y = pk2bf(v[2], v[3]);
    *(uint2*)(po + k * 64) = u;
  }
}

// ---------------------------------------------------------------------------
// Kernel 3: reduce 4 bf16 partials AND symmetrize in one pass:
//   accS[b] = A + A^T  where A = sum_g part[g][b]
// Grid (36 tile-pairs, 5): y<4 -> reduce+sym for batch y; y==4 -> structural
// softmax producing st (rows) and stT (transposed, for coalesced row reads
// of st columns in k_fusedx).
// ---------------------------------------------------------------------------
__global__ __launch_bounds__(256) void k_redsym(const ushort* __restrict__ part,
                                                const float* __restrict__ S,
                                                float* __restrict__ accS,
                                                float* __restrict__ st,
                                                float* __restrict__ stT) {
  __shared__ float LBUF[8704];  // 2 x 64x68 tiles; struct path uses 16x520
  const int tid = threadIdx.x;

  if (blockIdx.y == 4) {
    // structural softmax, 16-row strips; emit st and stT
    if (blockIdx.x >= 32) return;
    float* const sh = LBUF;
    const int i0 = blockIdx.x * 16;
    const int w = tid >> 6, lane = tid & 63;
#pragma unroll
    for (int rr = 0; rr < 4; ++rr) {
      const int r = w * 4 + rr;
      const float* Sp = S + (size_t)(i0 + r) * 512 + lane * 8;
      float4 a = *(const float4*)Sp;
      float4 c = *(const float4*)(Sp + 4);
      float m = fmaxf(fmaxf(fmaxf(a.x, a.y), fmaxf(a.z, a.w)),
                      fmaxf(fmaxf(c.x, c.y), fmaxf(c.z, c.w)));
#pragma unroll
      for (int off = 32; off > 0; off >>= 1) m = fmaxf(m, __shfl_xor(m, off));
      float e0 = __expf(a.x - m), e1 = __expf(a.y - m);
      float e2 = __expf(a.z - m), e3 = __expf(a.w - m);
      float e4 = __expf(c.x - m), e5 = __expf(c.y - m);
      float e6 = __expf(c.z - m), e7 = __expf(c.w - m);
      float s = ((e0 + e1) + (e2 + e3)) + ((e4 + e5) + (e6 + e7));
#pragma unroll
      for (int off = 32; off > 0; off >>= 1) s += __shfl_xor(s, off);
      float inv = 1.0f / s;
      float4 o1 = make_float4(e0 * inv, e1 * inv, e2 * inv, e3 * inv);
      float4 o2 = make_float4(e4 * inv, e5 * inv, e6 * inv, e7 * inv);
      float* op = st + (size_t)(i0 + r) * 512 + lane * 8;
      *(float4*)op = o1;
      *(float4*)(op + 4) = o2;
      float* shr = sh + r * 520 + lane * 8;
      *(float4*)shr = o1;
      *(float4*)(shr + 4) = o2;
    }
    __syncthreads();
#pragma unroll
    for (int pp = 0; pp < 2; ++pp) {
      const int j = tid + pp * 256;
      float4 t0 = make_float4(sh[0 * 520 + j],  sh[1 * 520 + j],
                              sh[2 * 520 + j],  sh[3 * 520 + j]);
      float4 t1 = make_float4(sh[4 * 520 + j],  sh[5 * 520 + j],
                              sh[6 * 520 + j],  sh[7 * 520 + j]);
      float4 t2 = make_float4(sh[8 * 520 + j],  sh[9 * 520 + j],
                              sh[10 * 520 + j], sh[11 * 520 + j]);
      float4 t3 = make_float4(sh[12 * 520 + j], sh[13 * 520 + j],
                              sh[14 * 520 + j], sh[15 * 520 + j]);
      float* op = stT + (size_t)j * 512 + i0;
      *(float4*)(op + 0)  = t0;
      *(float4*)(op + 4)  = t1;
      *(float4*)(op + 8)  = t2;
      *(float4*)(op + 12) = t3;
    }
    return;
  }

  // reduce over 4 groups + symmetrize (64x64 tile pair)
  float* const L1 = LBUF;
  float* const L2 = LBUF + 4352;
  const int b = blockIdx.y;
  int rem = blockIdx.x, ti = 0;
  for (;;) { int cnt = 8 - ti; if (rem < cnt) break; rem -= cnt; ++ti; }
  const int tj = ti + rem;
  const bool diag = (ti == tj);

#pragma unroll
  for (int it = 0; it < 4; ++it) {
    int L = tid * 4 + it * 1024;
    int r = L >> 6, c = L & 63;
    const ushort* p1 = part + ((size_t)b * 512 + ti * 64 + r) * 512 + tj * 64 + c;
    float s0 = 0.f, s1 = 0.f, s2 = 0.f, s3 = 0.f;
#pragma unroll
    for (int g = 0; g < 4; ++g) {
      ushort4 v = *(const ushort4*)(p1 + (size_t)g * 1048576);
      s0 += __uint_as_float((unsigned int)v.x << 16);
      s1 += __uint_as_float((unsigned int)v.y << 16);
      s2 += __uint_as_float((unsigned int)v.z << 16);
      s3 += __uint_as_float((unsigned int)v.w << 16);
    }
    *(float4*)(L1 + r * 68 + c) = make_float4(s0, s1, s2, s3);
    if (!diag) {
      const ushort* p2 = part + ((size_t)b * 512 + tj * 64 + r) * 512 + ti * 64 + c;
      float u0 = 0.f, u1 = 0.f, u2 = 0.f, u3 = 0.f;
#pragma unroll
      for (int g = 0; g < 4; ++g) {
        ushort4 v = *(const ushort4*)(p2 + (size_t)g * 1048576);
        u0 += __uint_as_float((unsigned int)v.x << 16);
        u1 += __uint_as_float((unsigned int)v.y << 16);
        u2 += __uint_as_float((unsigned int)v.z << 16);
        u3 += __uint_as_float((unsigned int)v.w << 16);
      }
      *(float4*)(L2 + r * 68 + c) = make_float4(u0, u1, u2, u3);
    }
  }
  __syncthreads();

  const float* LT = diag ? L1 : L2;
  float* M = accS + (size_t)b * 262144;
#pragma unroll
  for (int it = 0; it < 4; ++it) {
    int L = tid * 4 + it * 1024;
    int r = L >> 6, c = L & 63;
    float4 o1;
    o1.x = L1[r * 68 + c + 0] + LT[(c + 0) * 68 + r];
    o1.y = L1[r * 68 + c + 1] + LT[(c + 1) * 68 + r];
    o1.z = L1[r * 68 + c + 2] + LT[(c + 2) * 68 + r];
    o1.w = L1[r * 68 + c + 3] + LT[(c + 3) * 68 + r];
    *(float4*)(M + (ti * 64 + r) * 512 + tj * 64 + c) = o1;
    if (!diag) {
      float4 o2;
      o2.x = L2[r * 68 + c + 0] + L1[(c + 0) * 68 + r];
      o2.y = L2[r * 68 + c + 1] + L1[(c + 1) * 68 + r];
      o2.z = L2[r * 68 + c + 2] + L1[(c + 2) * 68 + r];
      o2.w = L2[r * 68 + c + 3] + L1[(c + 3) * 68 + r];
      *(float4*)(M + (tj * 64 + r) * 512 + ti * 64 + c) = o2;
    }
  }
}

// ---------------------------------------------------------------------------
// Block reductions
// ---------------------------------------------------------------------------
__device__ __forceinline__ float blk_max(float v, float* red, int tid) {
#pragma unroll
  for (int off = 32; off > 0; off >>= 1) v = fmaxf(v, __shfl_xor(v, off, 64));
  if ((tid & 63) == 0) red[tid >> 6] = v;
  __syncthreads();
  v = fmaxf(fmaxf(red[0], red[1]), fmaxf(red[2], red[3]));
  __syncthreads();
  return v;
}
__device__ __forceinline__ float blk_sum(float v, float* red, int tid) {
#pragma unroll
  for (int off = 32; off > 0; off >>= 1) v += __shfl_xor(v, off, 64);
  if ((tid & 63) == 0) red[tid >> 6] = v;
  __syncthreads();
  v = (red[0] + red[1]) + (red[2] + red[3]);
  __syncthreads();
  return v;
}

// ---------------------------------------------------------------------------
// Kernel 4: fused row softmax -> bf16, PLUS (blockIdx.x >= 512) the
// x[b,c,j,t] -> xtb[b,c,t,j] bf16 transpose (independent work, same
// dependency frontier, saves one launch).
// ---------------------------------------------------------------------------
__global__ __launch_bounds__(256) void k_fusedx(const float* __restrict__ accS,
                                                const float* __restrict__ st,
                                                const float* __restrict__ stT,
                                                const float* __restrict__ fw,
                                                const float* __restrict__ fb,
                                                const float* __restrict__ x,
                                                ushort* __restrict__ fusedb,
                                                ushort* __restrict__ xtb) {
  __shared__ ushort xs[16 * 520];
  __shared__ float red[4];
  const int tid = threadIdx.x;
  const int b = blockIdx.y;

  if (blockIdx.x >= 512) {
    // ---- xconv path ----
    const int c = blockIdx.x - 512;
    const float* in = x + ((size_t)b * 128 + c) * 8192;
    ushort* outp = xtb + ((size_t)b * 128 + c) * 8192;
#pragma unroll
    for (int it = 0; it < 8; ++it) {
      int idx = (tid + it * 256) * 4;
      int j = idx >> 4, t0 = idx & 15;
      float4 v = *(const float4*)(in + idx);
      xs[(t0 + 0) * 520 + j] = cv1(v.x);
      xs[(t0 + 1) * 520 + j] = cv1(v.y);
      xs[(t0 + 2) * 520 + j] = cv1(v.z);
      xs[(t0 + 3) * 520 + j] = cv1(v.w);
    }
    __syncthreads();
#pragma unroll
    for (int it = 0; it < 4; ++it) {
      int u = (tid + it * 256) * 8;
      int t = u >> 9, j0 = u & 511;
      *(uint4*)(outp + u) = *(const uint4*)(xs + t * 520 + j0);
    }
    return;
  }

  // ---- fused softmax path ----
  const int i = blockIdx.x;
  const float w0s = fw[0] * (0.5f / 64.f);
  const float w1s = fw[1] * 0.5f;
  const float bias = fb[0];
  const float* A = accS + (size_t)b * 262144 + (size_t)i * 512;
  float2 a2 = *(const float2*)(A + tid * 2);
  float2 s2 = *(const float2*)(st + (size_t)i * 512 + tid * 2);
  float2 t2 = *(const float2*)(stT + (size_t)i * 512 + tid * 2);
  float l0 = fmaf(w0s, a2.x, fmaf(w1s, s2.x + t2.x, bias));
  float l1 = fmaf(w0s, a2.y, fmaf(w1s, s2.y + t2.y, bias));
  float m = blk_max(fmaxf(l0, l1), red, tid);
  float e0 = __expf(l0 - m), e1 = __expf(l1 - m);
  float sum = blk_sum(e0 + e1, red, tid);
  float inv = 1.0f / sum;
  *(unsigned int*)(fusedb + ((size_t)(b * 512 + i)) * 512 + tid * 2) =
      pk2bf(e0 * inv, e1 * inv);
}

// ---------------------------------------------------------------------------
// Kernel 5: MFMA aggregation. out[b,c,i,t] = sum_j fusedb[b,i,j] * xtb[b,c,t,j]
// ---------------------------------------------------------------------------
__global__ __launch_bounds__(256) void k_agg(const ushort* __restrict__ fusedb,
                                             const ushort* __restrict__ xtb,
                                             float* __restrict__ out) {
  __shared__ ushort xs[16 * 520];
  const int cg = blockIdx.x;
  const int i0 = blockIdx.y * 64;
  const int b = blockIdx.z;
  const int tid = threadIdx.x, w = tid >> 6, lane = tid & 63;
  const int lm = lane & 15, quad = lane >> 4;

  const ushort* fr = fusedb + ((size_t)(b * 512 + i0 + w * 16 + lm)) * 512 + quad * 8;
  bf16x8 af[16];
#pragma unroll
  for (int kk = 0; kk < 16; ++kk) af[kk] = *(const bf16x8*)(fr + kk * 32);

  const ushort* xg = xtb + ((size_t)b * 128 + cg * 8) * 8192;
  uint4 rg[4];
#pragma unroll
  for (int it = 0; it < 4; ++it) rg[it] = *(const uint4*)(xg + (tid + it * 256) * 8);

  for (int c = 0; c < 8; ++c) {
#pragma unroll
    for (int it = 0; it < 4; ++it) {
      int u = (tid + it * 256) * 8;
      int t = u >> 9, j0 = u & 511;
      *(uint4*)(xs + t * 520 + j0) = rg[it];
    }
    __syncthreads();
    if (c < 7) {
      const ushort* xg2 = xg + (size_t)(c + 1) * 8192;
#pragma unroll
      for (int it = 0; it < 4; ++it) rg[it] = *(const uint4*)(xg2 + (tid + it * 256) * 8);
    }
    f32x4 acc = {0.f, 0.f, 0.f, 0.f};
#pragma unroll
    for (int kk = 0; kk < 16; ++kk) {
      bf16x8 bf = *(const bf16x8*)(xs + lm * 520 + kk * 32 + quad * 8);
      acc = __builtin_amdgcn_mfma_f32_16x16x32_bf16(af[kk], bf, acc, 0, 0, 0);
    }
    float* op = out + (size_t)b * 1048576 + (size_t)(cg * 8 + c) * 8192 +
                (size_t)(i0 + w * 16 + quad * 4) * 16 + lm;
    op[0]  = acc[0];
    op[16] = acc[1];
    op[32] = acc[2];
    op[48] = acc[3];
    __syncthreads();
  }
}

// ---------------------------------------------------------------------------
extern "C" void kernel_launch(void* const* d_in, const int* in_sizes, int n_in,
                              void* d_out, int out_size, void* d_ws, size_t ws_size,
                              hipStream_t stream) {
  const float* x  = (const float*)d_in[0];
  const float* Wq = (const float*)d_in[1];
  const float* Wk = (const float*)d_in[2];
  const float* S  = (const float*)d_in[3];
  const float* fw = (const float*)d_in[4];
  const float* fb = (const float*)d_in[5];
  float* out = (float*)d_out;

  // workspace layout (bytes):
  //  [0,8M)    Qb        (bf16)     -- later overlaid by xtb
  //  [8M,16M)  Kb        (bf16)
  //  [16M,24M) part      (bf16, 4 groups x 4 b x 512 x 512)
  //  [24M,28M) accS      (fp32, 4 b x 512 x 512, symmetrized sum)
  //  [28M,29M) st        (fp32)
  //  [29M,30M) stT       (fp32)
  //  [30M,32M) fusedb    (bf16)
  ushort* Qb   = (ushort*)d_ws;
  ushort* Kb   = Qb + 4194304;
  ushort* part = Kb + 4194304;
  ushort* xtb  = (ushort*)d_ws;  // overlay: Qb/Kb dead after k_scores
  float*  accS = (float*)((char*)d_ws + 25165824);
  float*  st   = accS + 1048576;
  float*  stT  = st + 262144;
  ushort* fusedb = (ushort*)(stT + 262144);

  k_proj  <<<dim3(64, 4),    256, 0, stream>>>(x, Wq, Wk, Qb, Kb);
  k_scores<<<dim3(32, 4, 4), 256, 0, stream>>>(Qb, Kb, part);
  k_redsym<<<dim3(36, 5),    256, 0, stream>>>(part, S, accS, st, stT);
  k_fusedx<<<dim3(640, 4),   256, 0, stream>>>(accS, st, stT, fw, fb, x, fusedb, xtb);
  k_agg   <<<dim3(16, 8, 4), 256, 0, stream>>>(fusedb, xtb, out);
}